// Round 6
// baseline (290.973 us; speedup 1.0000x reference)
//
#include <hip/hip_runtime.h>
#include <hip/hip_bf16.h>
#include <cstdint>
#include <cstddef>

typedef __attribute__((ext_vector_type(8))) short frag8;   // 8 x bf16 (4 VGPRs)
typedef __attribute__((ext_vector_type(4))) float facc4;   // MFMA accumulator

__device__ __forceinline__ float b2f(unsigned short u) {
  union { unsigned int i; float f; } v; v.i = ((unsigned int)u) << 16; return v.f;
}
__device__ __forceinline__ unsigned short f2b(float f) {
  union { float f; unsigned int i; } v; v.f = f;
  unsigned int u = v.i;
  unsigned int r = (u + 0x7fffu + ((u >> 16) & 1u)) >> 16;   // RNE
  return (unsigned short)r;
}
__device__ __forceinline__ unsigned long long pk4(float a, float b, float c, float d) {
  union { __hip_bfloat162 h2[2]; unsigned long long u; } pk;
  pk.h2[0] = __float22bfloat162_rn(float2{a, b});
  pk.h2[1] = __float22bfloat162_rn(float2{c, d});
  return pk.u;
}

// ---------------- prep kernels ----------------

__global__ void cvt_f32_bf16_k(const float* __restrict__ in, unsigned short* __restrict__ out, int n8) {
  int i = blockIdx.x * blockDim.x + threadIdx.x;
  if (i >= n8) return;
  const float4* p = (const float4*)in + (size_t)i * 2;
  float4 a = p[0], b = p[1];
  union { unsigned short u[8]; frag8 v; } o;
  o.u[0] = f2b(a.x); o.u[1] = f2b(a.y); o.u[2] = f2b(a.z); o.u[3] = f2b(a.w);
  o.u[4] = f2b(b.x); o.u[5] = f2b(b.y); o.u[6] = f2b(b.z); o.u[7] = f2b(b.w);
  *((frag8*)out + i) = o.v;
}

// W (R x Cn) f32  ->  Wt (Cn x R) bf16
__global__ void transpose_cvt_k(const float* __restrict__ W, unsigned short* __restrict__ Wt, int R, int Cn) {
  __shared__ float tile[32][33];
  int tx = threadIdx.x, ty = threadIdx.y;
  int c = blockIdx.x * 32 + tx;
  #pragma unroll
  for (int i = 0; i < 32; i += 8)
    tile[ty + i][tx] = W[(size_t)(blockIdx.y * 32 + ty + i) * Cn + c];
  __syncthreads();
  int rr = blockIdx.y * 32 + tx;
  #pragma unroll
  for (int i = 0; i < 32; i += 8)
    Wt[(size_t)(blockIdx.x * 32 + ty + i) * R + rr] = f2b(tile[tx][ty + i]);
}

__global__ void rope_tables_k(float* __restrict__ cosT, float* __restrict__ sinT) {
  int id = blockIdx.x * 256 + threadIdx.x;   // 1024*32
  int t = id >> 5, i = id & 31;
  float freq = powf(10000.0f, -(float)i * (1.0f / 32.0f));
  float a = (float)t * freq;
  cosT[id] = cosf(a);
  sinT[id] = sinf(a);
}

// Q,K layout: [bh=96][t=1024][d=64] bf16; rotate interleaved pairs
__global__ void rope_k(unsigned short* __restrict__ Q, unsigned short* __restrict__ Kb,
                       const float* __restrict__ cosT, const float* __restrict__ sinT) {
  int id = blockIdx.x * 256 + threadIdx.x;   // 96*1024*32
  int i = id & 31;
  int t = (id >> 5) & 1023;
  int bh = id >> 15;
  size_t base = ((size_t)bh << 16) + (size_t)t * 64 + i * 2;
  float c = cosT[(t << 5) + i], s = sinT[(t << 5) + i];
  unsigned int* qp = (unsigned int*)(Q + base);
  unsigned int qu = *qp;
  float q0 = b2f(qu & 0xffffu), q1 = b2f(qu >> 16);
  *qp = (unsigned int)f2b(q0 * c - q1 * s) | ((unsigned int)f2b(q1 * c + q0 * s) << 16);
  unsigned int* kp = (unsigned int*)(Kb + base);
  unsigned int ku = *kp;
  float k0 = b2f(ku & 0xffffu), k1 = b2f(ku >> 16);
  *kp = (unsigned int)f2b(k0 * c - k1 * s) | ((unsigned int)f2b(k1 * c + k0 * s) << 16);
}

// ---------------- GEMM: C = A(MxK) * Bt(NxK)^T + bias ----------------
// EPI 0: scatter to Q (scaled 0.125), K, V^T   EPI 1: fp32 out with bias

#define GLDK 72   // padded LDS stride: 144B = 9*16B -> aligned b128, 2-way-only bank conflicts

template<int EPI>
__global__ __launch_bounds__(256)
void gemm128_k(const unsigned short* __restrict__ A, const unsigned short* __restrict__ Bt,
               const float* __restrict__ bias, float* __restrict__ outF,
               unsigned short* __restrict__ Qo, unsigned short* __restrict__ Ko,
               unsigned short* __restrict__ Vo, int M, int N, int K)
{
  __shared__ unsigned short As[128 * GLDK];
  __shared__ unsigned short Bs[128 * GLDK];
  const int tid = threadIdx.x;
  const int lane = tid & 63;
  const int w = tid >> 6, wm = w >> 1, wn = w & 1;
  const int g = lane >> 4, cL = lane & 15;

  // bijective XCD swizzle (nwg % 8 == 0 for both grids)
  const int nwg = gridDim.x * gridDim.y;
  const int flat = blockIdx.y * gridDim.x + blockIdx.x;
  const int cpx = nwg >> 3;
  const int swz = (flat & 7) * cpx + (flat >> 3);
  const int tM = (swz / gridDim.x) * 128, tN = (swz % gridDim.x) * 128;

  facc4 zero4 = {0.f, 0.f, 0.f, 0.f};
  facc4 acc[4][4];
  #pragma unroll
  for (int i = 0; i < 4; ++i)
    #pragma unroll
    for (int j = 0; j < 4; ++j) acc[i][j] = zero4;

  const int sr = tid >> 3;          // staging row 0..31 (+32 per chunk)
  const int sc = (tid & 7) * 8;     // staging col

  for (int k0 = 0; k0 < K; k0 += 64) {
    #pragma unroll
    for (int ch = 0; ch < 4; ++ch) {
      int r = sr + ch * 32;
      frag8 va = *(const frag8*)(A  + (size_t)(tM + r) * K + k0 + sc);
      frag8 vb = *(const frag8*)(Bt + (size_t)(tN + r) * K + k0 + sc);
      *(frag8*)(&As[r * GLDK + sc]) = va;
      *(frag8*)(&Bs[r * GLDK + sc]) = vb;
    }
    __syncthreads();
    #pragma unroll
    for (int kk = 0; kk < 2; ++kk) {
      frag8 af[4], bfr[4];
      #pragma unroll
      for (int i = 0; i < 4; ++i)
        af[i] = *(const frag8*)(&As[(wm * 64 + i * 16 + cL) * GLDK + kk * 32 + g * 8]);
      #pragma unroll
      for (int j = 0; j < 4; ++j)
        bfr[j] = *(const frag8*)(&Bs[(wn * 64 + j * 16 + cL) * GLDK + kk * 32 + g * 8]);
      #pragma unroll
      for (int i = 0; i < 4; ++i)
        #pragma unroll
        for (int j = 0; j < 4; ++j)
          acc[i][j] = __builtin_amdgcn_mfma_f32_16x16x32_bf16(af[i], bfr[j], acc[i][j], 0, 0, 0);
    }
    __syncthreads();
  }

  #pragma unroll
  for (int i = 0; i < 4; ++i) {
    #pragma unroll
    for (int j = 0; j < 4; ++j) {
      const int col = tN + wn * 64 + j * 16 + cL;
      const float bv = bias[col];
      if constexpr (EPI == 0) {
        const int sel = col / 768;
        const int cc = col - sel * 768;
        const int h = cc >> 6, d = cc & 63;
        #pragma unroll
        for (int r = 0; r < 4; ++r) {
          const int m = tM + wm * 64 + i * 16 + g * 4 + r;
          const float v = acc[i][j][r] + bv;
          const int b = m >> 10, t = m & 1023;
          const size_t hb = ((size_t)(b * 12 + h)) << 16;
          if (sel == 0)      Qo[hb + (size_t)t * 64 + d] = f2b(v * 0.125f);  // fold D^-0.5
          else if (sel == 1) Ko[hb + (size_t)t * 64 + d] = f2b(v);
          else               Vo[hb + ((size_t)d << 10) + t] = f2b(v);        // V^T
        }
      } else {
        #pragma unroll
        for (int r = 0; r < 4; ++r) {
          const int m = tM + wm * 64 + i * 16 + g * 4 + r;
          outF[(size_t)m * N + col] = acc[i][j][r] + bv;
        }
      }
    }
  }
}

// ---------------- flash attention (swapped-operand, lane-local softmax) ----
// Q,K: [bh][t][d] bf16 (Q pre-scaled by 0.125), Vt: [bh][d][t] bf16
// S^T = mfma(K, Q): lane(cL,g) holds S[q=cL][k=j*16+g*4+r] -> per-lane q-row.
// O^T = mfma(Vt, P): lane(cL,g) holds O[q=cL][d=jd*16+g*4+r].
// Softmax: 15 in-lane ops + shfl_xor(16),(32). m/l/scale are per-lane scalars.
// XCD-affinity grid; heavy (qb=15) blocks first.

__global__ __launch_bounds__(256, 4)
void attn_k(const unsigned short* __restrict__ Q, const unsigned short* __restrict__ Kb,
            const unsigned short* __restrict__ Vt, unsigned short* __restrict__ Y)
{
  __shared__ unsigned short Pl[4 * 16 * GLDK];   // per-wave P tile, padded stride
  const int tid = threadIdx.x, lane = tid & 63, w = tid >> 6;
  const int g = lane >> 4, cL = lane & 15;

  // XCD-affinity mapping: bid -> (head, qb)
  const int bid = blockIdx.x;            // 0..1535
  const int xcd = bid & 7;
  const int slot = bid >> 3;             // 0..191
  const int bh = xcd + 8 * (slot % 12);  // head 0..95, fixed per XCD
  const int qb = 15 - slot / 12;         // heavy-first
  const int qw = qb * 64 + w * 16;
  const size_t hb = ((size_t)bh) << 16;

  frag8 qf[2];
  #pragma unroll
  for (int ks = 0; ks < 2; ++ks)
    qf[ks] = *(const frag8*)(Q + hb + (size_t)(qw + cL) * 64 + ks * 32 + g * 8);

  const unsigned short* Kp = Kb + hb + (size_t)cL * 64 + g * 8;
  const unsigned short* Vp = Vt + hb + (size_t)cL * 1024 + g * 8;
  unsigned short* PlW = &Pl[w * (16 * GLDK)];

  facc4 zero4 = {0.f, 0.f, 0.f, 0.f};
  facc4 o[4];
  #pragma unroll
  for (int jd = 0; jd < 4; ++jd) o[jd] = zero4;
  float mrow = -1e30f, lrow = 0.f;

  const int ntiles = qb + 1;   // causal
  for (int it = 0; it < ntiles; ++it) {
    const int kv0 = it * 64;
    // K loads (8 x b128)
    frag8 kf[2][4];
    #pragma unroll
    for (int ks = 0; ks < 2; ++ks)
      #pragma unroll
      for (int j = 0; j < 4; ++j)
        kf[ks][j] = *(const frag8*)(Kp + (size_t)(kv0 + j * 16) * 64 + ks * 32);
    // QK^T (swapped): S^T tile, lane-local q-row
    facc4 s[4];
    #pragma unroll
    for (int j = 0; j < 4; ++j) s[j] = zero4;
    #pragma unroll
    for (int ks = 0; ks < 2; ++ks)
      #pragma unroll
      for (int j = 0; j < 4; ++j)
        s[j] = __builtin_amdgcn_mfma_f32_16x16x32_bf16(kf[ks][j], qf[ks], s[j], 0, 0, 0);
    // V loads issued now; consumed after softmax (latency hidden)
    frag8 vf[2][4];
    #pragma unroll
    for (int ks = 0; ks < 2; ++ks)
      #pragma unroll
      for (int jd = 0; jd < 4; ++jd)
        vf[ks][jd] = *(const frag8*)(Vp + (size_t)(jd * 16) * 1024 + kv0 + ks * 32);

    if (kv0 + 63 > qw) {               // diagonal tile: causal mask (k > q)
      const int qrow = qw + cL;
      #pragma unroll
      for (int j = 0; j < 4; ++j)
        #pragma unroll
        for (int r = 0; r < 4; ++r)
          if (kv0 + j * 16 + g * 4 + r > qrow) s[j][r] = -1e30f;
    }
    // row max: in-lane over 16 + cross-g (2 shfl)
    float pm = fmaxf(fmaxf(fmaxf(s[0][0], s[0][1]), fmaxf(s[0][2], s[0][3])),
                     fmaxf(fmaxf(s[1][0], s[1][1]), fmaxf(s[1][2], s[1][3])));
    pm = fmaxf(pm, fmaxf(fmaxf(fmaxf(s[2][0], s[2][1]), fmaxf(s[2][2], s[2][3])),
                         fmaxf(fmaxf(s[3][0], s[3][1]), fmaxf(s[3][2], s[3][3]))));
    pm = fmaxf(pm, __shfl_xor(pm, 16));
    pm = fmaxf(pm, __shfl_xor(pm, 32));

    const float mn = fmaxf(mrow, pm);
    const float sc_ = __expf(mrow - mn);
    mrow = mn;
    float rs = 0.f;
    #pragma unroll
    for (int j = 0; j < 4; ++j)
      #pragma unroll
      for (int r = 0; r < 4; ++r) {
        const float p = __expf(s[j][r] - mn);
        s[j][r] = p;
        rs += p;
      }
    // pack P -> LDS (4 x b64), layout: P_lds[q=cL][k] for PV B-frag reads
    #pragma unroll
    for (int j = 0; j < 4; ++j)
      *(unsigned long long*)(&PlW[cL * GLDK + j * 16 + g * 4]) =
          pk4(s[j][0], s[j][1], s[j][2], s[j][3]);
    rs += __shfl_xor(rs, 16);
    rs += __shfl_xor(rs, 32);
    lrow = lrow * sc_ + rs;
    #pragma unroll
    for (int jd = 0; jd < 4; ++jd)
      #pragma unroll
      for (int r = 0; r < 4; ++r)
        o[jd][r] *= sc_;
    // PV (swapped): O^T = Vt * P^T -> lane-local q
    #pragma unroll
    for (int ks = 0; ks < 2; ++ks) {
      frag8 pa = *(const frag8*)(&PlW[cL * GLDK + ks * 32 + g * 8]);
      #pragma unroll
      for (int jd = 0; jd < 4; ++jd)
        o[jd] = __builtin_amdgcn_mfma_f32_16x16x32_bf16(vf[ks][jd], pa, o[jd], 0, 0, 0);
    }
  }

  const int b = bh / 12, h = bh - (bh / 12) * 12;
  const float inv = 1.0f / lrow;       // per-lane scalar (q = qw+cL)
  const size_t yrow = (size_t)(b * 1024 + qw + cL) * 768 + h * 64;
  #pragma unroll
  for (int jd = 0; jd < 4; ++jd)
    *(unsigned long long*)(&Y[yrow + jd * 16 + g * 4]) =
        pk4(o[jd][0] * inv, o[jd][1] * inv, o[jd][2] * inv, o[jd][3] * inv);
}

// ---------------- launch ----------------

extern "C" void kernel_launch(void* const* d_in, const int* in_sizes, int n_in,
                              void* d_out, int out_size, void* d_ws, size_t ws_size,
                              hipStream_t stream) {
  const float* x      = (const float*)d_in[0];
  const float* W_attn = (const float*)d_in[1];
  const float* b_attn = (const float*)d_in[2];
  const float* W_proj = (const float*)d_in[3];
  const float* b_proj = (const float*)d_in[4];
  float* out = (float*)d_out;
  char* ws = (char*)d_ws;

  unsigned short* xb  = (unsigned short*)(ws);               // 8192x768 bf16
  unsigned short* WtA = (unsigned short*)(ws + 12582912);    // 2304x768 bf16
  unsigned short* WtP = (unsigned short*)(ws + 16121856);    // 768x768 bf16
  unsigned short* Qb  = (unsigned short*)(ws + 17301504);    // 96x1024x64 bf16
  unsigned short* Kb  = (unsigned short*)(ws + 29884416);
  unsigned short* Vt  = (unsigned short*)(ws + 42467328);    // transposed V
  unsigned short* Yb  = (unsigned short*)(ws + 55050240);    // 8192x768 bf16
  float* cosT = (float*)(ws + 67633152);                     // 1024x32 f32
  float* sinT = (float*)(ws + 67764224);

  cvt_f32_bf16_k<<<3072, 256, 0, stream>>>(x, xb, 786432);
  transpose_cvt_k<<<dim3(72, 24), dim3(32, 8), 0, stream>>>(W_attn, WtA, 768, 2304);
  transpose_cvt_k<<<dim3(24, 24), dim3(32, 8), 0, stream>>>(W_proj, WtP, 768, 768);
  rope_tables_k<<<128, 256, 0, stream>>>(cosT, sinT);
  gemm128_k<0><<<dim3(18, 64), 256, 0, stream>>>(xb, WtA, b_attn, nullptr, Qb, Kb, Vt, 8192, 2304, 768);
  rope_k<<<12288, 256, 0, stream>>>(Qb, Kb, cosT, sinT);
  attn_k<<<1536, 256, 0, stream>>>(Qb, Kb, Vt, Yb);
  gemm128_k<1><<<dim3(6, 64), 256, 0, stream>>>(Yb, WtP, b_proj, out, nullptr, nullptr, nullptr, 8192, 768, 768);
}

// Round 8
// 281.564 us; speedup vs baseline: 1.0334x; 1.0334x over previous
//
#include <hip/hip_runtime.h>
#include <hip/hip_bf16.h>
#include <cstdint>
#include <cstddef>

typedef __attribute__((ext_vector_type(8))) short frag8;   // 8 x bf16 (4 VGPRs)
typedef __attribute__((ext_vector_type(4))) float facc4;   // MFMA accumulator

__device__ __forceinline__ float b2f(unsigned short u) {
  union { unsigned int i; float f; } v; v.i = ((unsigned int)u) << 16; return v.f;
}
__device__ __forceinline__ unsigned short f2b(float f) {
  union { float f; unsigned int i; } v; v.f = f;
  unsigned int u = v.i;
  unsigned int r = (u + 0x7fffu + ((u >> 16) & 1u)) >> 16;   // RNE
  return (unsigned short)r;
}
__device__ __forceinline__ unsigned long long pk4(float a, float b, float c, float d) {
  union { __hip_bfloat162 h2[2]; unsigned long long u; } pk;
  pk.h2[0] = __float22bfloat162_rn(float2{a, b});
  pk.h2[1] = __float22bfloat162_rn(float2{c, d});
  return pk.u;
}

// ---------------- prep kernels ----------------

__global__ void cvt_f32_bf16_k(const float* __restrict__ in, unsigned short* __restrict__ out, int n8) {
  int i = blockIdx.x * blockDim.x + threadIdx.x;
  if (i >= n8) return;
  const float4* p = (const float4*)in + (size_t)i * 2;
  float4 a = p[0], b = p[1];
  union { unsigned short u[8]; frag8 v; } o;
  o.u[0] = f2b(a.x); o.u[1] = f2b(a.y); o.u[2] = f2b(a.z); o.u[3] = f2b(a.w);
  o.u[4] = f2b(b.x); o.u[5] = f2b(b.y); o.u[6] = f2b(b.z); o.u[7] = f2b(b.w);
  *((frag8*)out + i) = o.v;
}

// W (R x Cn) f32  ->  Wt (Cn x R) bf16
__global__ void transpose_cvt_k(const float* __restrict__ W, unsigned short* __restrict__ Wt, int R, int Cn) {
  __shared__ float tile[32][33];
  int tx = threadIdx.x, ty = threadIdx.y;
  int c = blockIdx.x * 32 + tx;
  #pragma unroll
  for (int i = 0; i < 32; i += 8)
    tile[ty + i][tx] = W[(size_t)(blockIdx.y * 32 + ty + i) * Cn + c];
  __syncthreads();
  int rr = blockIdx.y * 32 + tx;
  #pragma unroll
  for (int i = 0; i < 32; i += 8)
    Wt[(size_t)(blockIdx.x * 32 + ty + i) * R + rr] = f2b(tile[tx][ty + i]);
}

__global__ void rope_tables_k(float* __restrict__ cosT, float* __restrict__ sinT) {
  int id = blockIdx.x * 256 + threadIdx.x;   // 1024*32
  int t = id >> 5, i = id & 31;
  float freq = powf(10000.0f, -(float)i * (1.0f / 32.0f));
  float a = (float)t * freq;
  cosT[id] = cosf(a);
  sinT[id] = sinf(a);
}

// Q,K layout: [bh=96][t=1024][d=64] bf16; rotate interleaved pairs
__global__ void rope_k(unsigned short* __restrict__ Q, unsigned short* __restrict__ Kb,
                       const float* __restrict__ cosT, const float* __restrict__ sinT) {
  int id = blockIdx.x * 256 + threadIdx.x;   // 96*1024*32
  int i = id & 31;
  int t = (id >> 5) & 1023;
  int bh = id >> 15;
  size_t base = ((size_t)bh << 16) + (size_t)t * 64 + i * 2;
  float c = cosT[(t << 5) + i], s = sinT[(t << 5) + i];
  unsigned int* qp = (unsigned int*)(Q + base);
  unsigned int qu = *qp;
  float q0 = b2f(qu & 0xffffu), q1 = b2f(qu >> 16);
  *qp = (unsigned int)f2b(q0 * c - q1 * s) | ((unsigned int)f2b(q1 * c + q0 * s) << 16);
  unsigned int* kp = (unsigned int*)(Kb + base);
  unsigned int ku = *kp;
  float k0 = b2f(ku & 0xffffu), k1 = b2f(ku >> 16);
  *kp = (unsigned int)f2b(k0 * c - k1 * s) | ((unsigned int)f2b(k1 * c + k0 * s) << 16);
}

// ---------------- GEMM: C = A(MxK) * Bt(NxK)^T + bias ----------------
// EPI 0: scatter to Q (scaled 0.125), K, V^T   EPI 1: fp32 out with bias

#define GLDK 72   // padded LDS stride: 144B = 9*16B -> aligned b128, 2-way-only bank conflicts

template<int EPI>
__global__ __launch_bounds__(256)
void gemm128_k(const unsigned short* __restrict__ A, const unsigned short* __restrict__ Bt,
               const float* __restrict__ bias, float* __restrict__ outF,
               unsigned short* __restrict__ Qo, unsigned short* __restrict__ Ko,
               unsigned short* __restrict__ Vo, int M, int N, int K)
{
  __shared__ unsigned short As[128 * GLDK];
  __shared__ unsigned short Bs[128 * GLDK];
  const int tid = threadIdx.x;
  const int lane = tid & 63;
  const int w = tid >> 6, wm = w >> 1, wn = w & 1;
  const int g = lane >> 4, cL = lane & 15;

  // bijective XCD swizzle (nwg % 8 == 0 for both grids)
  const int nwg = gridDim.x * gridDim.y;
  const int flat = blockIdx.y * gridDim.x + blockIdx.x;
  const int cpx = nwg >> 3;
  const int swz = (flat & 7) * cpx + (flat >> 3);
  const int tM = (swz / gridDim.x) * 128, tN = (swz % gridDim.x) * 128;

  facc4 zero4 = {0.f, 0.f, 0.f, 0.f};
  facc4 acc[4][4];
  #pragma unroll
  for (int i = 0; i < 4; ++i)
    #pragma unroll
    for (int j = 0; j < 4; ++j) acc[i][j] = zero4;

  const int sr = tid >> 3;          // staging row 0..31 (+32 per chunk)
  const int sc = (tid & 7) * 8;     // staging col

  for (int k0 = 0; k0 < K; k0 += 64) {
    #pragma unroll
    for (int ch = 0; ch < 4; ++ch) {
      int r = sr + ch * 32;
      frag8 va = *(const frag8*)(A  + (size_t)(tM + r) * K + k0 + sc);
      frag8 vb = *(const frag8*)(Bt + (size_t)(tN + r) * K + k0 + sc);
      *(frag8*)(&As[r * GLDK + sc]) = va;
      *(frag8*)(&Bs[r * GLDK + sc]) = vb;
    }
    __syncthreads();
    #pragma unroll
    for (int kk = 0; kk < 2; ++kk) {
      frag8 af[4], bfr[4];
      #pragma unroll
      for (int i = 0; i < 4; ++i)
        af[i] = *(const frag8*)(&As[(wm * 64 + i * 16 + cL) * GLDK + kk * 32 + g * 8]);
      #pragma unroll
      for (int j = 0; j < 4; ++j)
        bfr[j] = *(const frag8*)(&Bs[(wn * 64 + j * 16 + cL) * GLDK + kk * 32 + g * 8]);
      #pragma unroll
      for (int i = 0; i < 4; ++i)
        #pragma unroll
        for (int j = 0; j < 4; ++j)
          acc[i][j] = __builtin_amdgcn_mfma_f32_16x16x32_bf16(af[i], bfr[j], acc[i][j], 0, 0, 0);
    }
    __syncthreads();
  }

  #pragma unroll
  for (int i = 0; i < 4; ++i) {
    #pragma unroll
    for (int j = 0; j < 4; ++j) {
      const int col = tN + wn * 64 + j * 16 + cL;
      const float bv = bias[col];
      if constexpr (EPI == 0) {
        const int sel = col / 768;
        const int cc = col - sel * 768;
        const int h = cc >> 6, d = cc & 63;
        #pragma unroll
        for (int r = 0; r < 4; ++r) {
          const int m = tM + wm * 64 + i * 16 + g * 4 + r;
          const float v = acc[i][j][r] + bv;
          const int b = m >> 10, t = m & 1023;
          const size_t hb = ((size_t)(b * 12 + h)) << 16;
          if (sel == 0)      Qo[hb + (size_t)t * 64 + d] = f2b(v * 0.125f);  // fold D^-0.5
          else if (sel == 1) Ko[hb + (size_t)t * 64 + d] = f2b(v);
          else               Vo[hb + ((size_t)d << 10) + t] = f2b(v);        // V^T
        }
      } else {
        #pragma unroll
        for (int r = 0; r < 4; ++r) {
          const int m = tM + wm * 64 + i * 16 + g * 4 + r;
          outF[(size_t)m * N + col] = acc[i][j][r] + bv;
        }
      }
    }
  }
}

// ---------------- flash attention (paired q-blocks, K-prefetch) ----------
// Q,K: [bh][t][d] bf16 (Q pre-scaled 0.125), Vt: [bh][d][t] bf16.
// Swapped MFMA operands -> lane-local q-row softmax (verified r6).
// Pairing: block handles q-block A=15-x (ntA=16-x tiles) and B=x (ntB=x+1).
// ntA+ntB = 17 for every block -> uniform work, no tail; B's KV range is a
// prefix of A's -> shared K/V tiles (2x compute per load on overlap).
// K[it+1] prefetched into regs during iter it (V issued first so the
// compiler's counted vmcnt keeps the K-prefetch in flight across PV).

__device__ __forceinline__ void sm_pv(facc4 (&s)[4], frag8 (&vf)[2][4],
                                      unsigned short* PlW, int g, int cL,
                                      float& m, float& l, facc4 (&o)[4]) {
  float pm = fmaxf(fmaxf(fmaxf(s[0][0], s[0][1]), fmaxf(s[0][2], s[0][3])),
                   fmaxf(fmaxf(s[1][0], s[1][1]), fmaxf(s[1][2], s[1][3])));
  pm = fmaxf(pm, fmaxf(fmaxf(fmaxf(s[2][0], s[2][1]), fmaxf(s[2][2], s[2][3])),
                       fmaxf(fmaxf(s[3][0], s[3][1]), fmaxf(s[3][2], s[3][3]))));
  pm = fmaxf(pm, __shfl_xor(pm, 16));
  pm = fmaxf(pm, __shfl_xor(pm, 32));
  const float mn = fmaxf(m, pm);
  const float sc_ = __expf(m - mn);
  m = mn;
  float rs = 0.f;
  #pragma unroll
  for (int j = 0; j < 4; ++j)
    #pragma unroll
    for (int r = 0; r < 4; ++r) {
      const float p = __expf(s[j][r] - mn);
      s[j][r] = p;
      rs += p;
    }
  #pragma unroll
  for (int j = 0; j < 4; ++j)
    *(unsigned long long*)(&PlW[cL * GLDK + j * 16 + g * 4]) =
        pk4(s[j][0], s[j][1], s[j][2], s[j][3]);
  rs += __shfl_xor(rs, 16);
  rs += __shfl_xor(rs, 32);
  l = l * sc_ + rs;
  #pragma unroll
  for (int jd = 0; jd < 4; ++jd)
    #pragma unroll
    for (int r = 0; r < 4; ++r)
      o[jd][r] *= sc_;
  #pragma unroll
  for (int ks = 0; ks < 2; ++ks) {
    frag8 pa = *(const frag8*)(&PlW[cL * GLDK + ks * 32 + g * 8]);
    #pragma unroll
    for (int jd = 0; jd < 4; ++jd)
      o[jd] = __builtin_amdgcn_mfma_f32_16x16x32_bf16(vf[ks][jd], pa, o[jd], 0, 0, 0);
  }
}

__global__ __launch_bounds__(256, 3)
void attn_k(const unsigned short* __restrict__ Q, const unsigned short* __restrict__ Kb,
            const unsigned short* __restrict__ Vt, unsigned short* __restrict__ Y)
{
  __shared__ unsigned short Pl[8 * 16 * GLDK];   // per-wave A/B P tiles
  const int tid = threadIdx.x, lane = tid & 63, w = tid >> 6;
  const int g = lane >> 4, cL = lane & 15;

  // XCD-affinity mapping: bid -> (head, pair x)
  const int bid = blockIdx.x;            // 0..767
  const int xcd = bid & 7;
  const int slot = bid >> 3;             // 0..95
  const int bh = xcd + 8 * (slot % 12);  // head, fixed per XCD
  const int x = slot / 12;               // 0..7
  const int qwA = (15 - x) * 64 + w * 16;
  const int qwB = x * 64 + w * 16;
  const int ntA = 16 - x, ntB = x + 1;   // ntB <= 8 <= ntA
  const size_t hb = ((size_t)bh) << 16;

  frag8 qfA[2], qfB[2];
  #pragma unroll
  for (int ks = 0; ks < 2; ++ks) {
    qfA[ks] = *(const frag8*)(Q + hb + (size_t)(qwA + cL) * 64 + ks * 32 + g * 8);
    qfB[ks] = *(const frag8*)(Q + hb + (size_t)(qwB + cL) * 64 + ks * 32 + g * 8);
  }

  const unsigned short* Kp = Kb + hb + (size_t)cL * 64 + g * 8;
  const unsigned short* Vp = Vt + hb + (size_t)cL * 1024 + g * 8;
  unsigned short* PlA = &Pl[w * (16 * GLDK)];
  unsigned short* PlB = &Pl[(4 + w) * (16 * GLDK)];

  facc4 zero4 = {0.f, 0.f, 0.f, 0.f};
  facc4 oA[4], oB[4];
  #pragma unroll
  for (int jd = 0; jd < 4; ++jd) { oA[jd] = zero4; oB[jd] = zero4; }
  float mA = -1e30f, lA = 0.f, mB = -1e30f, lB = 0.f;

  // preload K tile 0
  frag8 kf[2][4];
  #pragma unroll
  for (int ks = 0; ks < 2; ++ks)
    #pragma unroll
    for (int j = 0; j < 4; ++j)
      kf[ks][j] = *(const frag8*)(Kp + (size_t)(j * 16) * 64 + ks * 32);

  for (int it = 0; it < ntA; ++it) {
    const int kv0 = it * 64;
    const bool doB = (it < ntB);         // block-uniform branch
    // QK^T for A (and B) from current kf
    facc4 sA[4], sB[4];
    #pragma unroll
    for (int j = 0; j < 4; ++j) { sA[j] = zero4; sB[j] = zero4; }
    #pragma unroll
    for (int ks = 0; ks < 2; ++ks)
      #pragma unroll
      for (int j = 0; j < 4; ++j)
        sA[j] = __builtin_amdgcn_mfma_f32_16x16x32_bf16(kf[ks][j], qfA[ks], sA[j], 0, 0, 0);
    if (doB) {
      #pragma unroll
      for (int ks = 0; ks < 2; ++ks)
        #pragma unroll
        for (int j = 0; j < 4; ++j)
          sB[j] = __builtin_amdgcn_mfma_f32_16x16x32_bf16(kf[ks][j], qfB[ks], sB[j], 0, 0, 0);
    }
    // V loads for this tile (consumed after softmax; latency hidden)
    frag8 vf[2][4];
    #pragma unroll
    for (int ks = 0; ks < 2; ++ks)
      #pragma unroll
      for (int jd = 0; jd < 4; ++jd)
        vf[ks][jd] = *(const frag8*)(Vp + (size_t)(jd * 16) * 1024 + kv0 + ks * 32);
    // K prefetch for next tile (issued after V so vmcnt(8) keeps it in flight)
    if (it + 1 < ntA) {
      const int kn = (it + 1) * 64;
      #pragma unroll
      for (int ks = 0; ks < 2; ++ks)
        #pragma unroll
        for (int j = 0; j < 4; ++j)
          kf[ks][j] = *(const frag8*)(Kp + (size_t)(kn + j * 16) * 64 + ks * 32);
    }
    // causal masks (diagonal tiles only)
    if (kv0 + 63 > qwA) {
      const int qrow = qwA + cL;
      #pragma unroll
      for (int j = 0; j < 4; ++j)
        #pragma unroll
        for (int r = 0; r < 4; ++r)
          if (kv0 + j * 16 + g * 4 + r > qrow) sA[j][r] = -1e30f;
    }
    if (doB && kv0 + 63 > qwB) {
      const int qrow = qwB + cL;
      #pragma unroll
      for (int j = 0; j < 4; ++j)
        #pragma unroll
        for (int r = 0; r < 4; ++r)
          if (kv0 + j * 16 + g * 4 + r > qrow) sB[j][r] = -1e30f;
    }
    // softmax + PV (A always, B on prefix) — independent chains interleave
    sm_pv(sA, vf, PlA, g, cL, mA, lA, oA);
    if (doB) sm_pv(sB, vf, PlB, g, cL, mB, lB, oB);
  }

  const int b = bh / 12, h = bh - (bh / 12) * 12;
  const float invA = 1.0f / lA;
  const size_t yrowA = (size_t)(b * 1024 + qwA + cL) * 768 + h * 64;
  #pragma unroll
  for (int jd = 0; jd < 4; ++jd)
    *(unsigned long long*)(&Y[yrowA + jd * 16 + g * 4]) =
        pk4(oA[jd][0] * invA, oA[jd][1] * invA, oA[jd][2] * invA, oA[jd][3] * invA);
  const float invB = 1.0f / lB;
  const size_t yrowB = (size_t)(b * 1024 + qwB + cL) * 768 + h * 64;
  #pragma unroll
  for (int jd = 0; jd < 4; ++jd)
    *(unsigned long long*)(&Y[yrowB + jd * 16 + g * 4]) =
        pk4(oB[jd][0] * invB, oB[jd][1] * invB, oB[jd][2] * invB, oB[jd][3] * invB);
}

// ---------------- launch ----------------

extern "C" void kernel_launch(void* const* d_in, const int* in_sizes, int n_in,
                              void* d_out, int out_size, void* d_ws, size_t ws_size,
                              hipStream_t stream) {
  const float* x      = (const float*)d_in[0];
  const float* W_attn = (const float*)d_in[1];
  const float* b_attn = (const float*)d_in[2];
  const float* W_proj = (const float*)d_in[3];
  const float* b_proj = (const float*)d_in[4];
  float* out = (float*)d_out;
  char* ws = (char*)d_ws;

  unsigned short* xb  = (unsigned short*)(ws);               // 8192x768 bf16
  unsigned short* WtA = (unsigned short*)(ws + 12582912);    // 2304x768 bf16
  unsigned short* WtP = (unsigned short*)(ws + 16121856);    // 768x768 bf16
  unsigned short* Qb  = (unsigned short*)(ws + 17301504);    // 96x1024x64 bf16
  unsigned short* Kb  = (unsigned short*)(ws + 29884416);
  unsigned short* Vt  = (unsigned short*)(ws + 42467328);    // transposed V
  unsigned short* Yb  = (unsigned short*)(ws + 55050240);    // 8192x768 bf16
  float* cosT = (float*)(ws + 67633152);                     // 1024x32 f32
  float* sinT = (float*)(ws + 67764224);

  cvt_f32_bf16_k<<<3072, 256, 0, stream>>>(x, xb, 786432);
  transpose_cvt_k<<<dim3(72, 24), dim3(32, 8), 0, stream>>>(W_attn, WtA, 768, 2304);
  transpose_cvt_k<<<dim3(24, 24), dim3(32, 8), 0, stream>>>(W_proj, WtP, 768, 768);
  rope_tables_k<<<128, 256, 0, stream>>>(cosT, sinT);
  gemm128_k<0><<<dim3(18, 64), 256, 0, stream>>>(xb, WtA, b_attn, nullptr, Qb, Kb, Vt, 8192, 2304, 768);
  rope_k<<<12288, 256, 0, stream>>>(Qb, Kb, cosT, sinT);
  attn_k<<<768, 256, 0, stream>>>(Qb, Kb, Vt, Yb);
  gemm128_k<1><<<dim3(6, 64), 256, 0, stream>>>(Yb, WtP, b_proj, out, nullptr, nullptr, nullptr, 8192, 768, 768);
}